// Round 1
// baseline (3215.163 us; speedup 1.0000x reference)
//
#include <hip/hip_runtime.h>
#include <math.h>

// Problem constants (fixed by setup_inputs)
#define B_   8
#define T_   2048
#define J_   17
#define D_   129          // d + 1
#define d_   128
#define H_   8
#define DH   16
#define BJ_  (B_ * J_)    // 136
#define EPS_ 1e-6f

// phi(x) = elu(x) + 1 = x+1 if x>0 else exp(x)
__device__ __forceinline__ float phi_f(float x) {
    return x > 0.f ? x + 1.f : __expf(x);
}

// --------------------------------------------------------------------------
// Kernel 1: for each (bj, t-chunk): compute k_m, v rows on the fly
// (qkv cols 128..383), accumulate kv[bj][h][i][j] = sum_t k_m[t,i]*v[t,j]
// and ksum[bj][h*16+i] = sum_t k_m[t,i] into workspace via atomics.
// Grid: (8 chunks, 136 bj), block 256.
// Thread c owns w_qkv row (128+c) in VGPRs; x-row loads are block-uniform
// -> scalar (s_load) broadcast; inner loop is pure v_fmac.
// --------------------------------------------------------------------------
__global__ __launch_bounds__(256) void k1_kv(
        const float* __restrict__ x,
        const float* __restrict__ w_qkv,
        const float* __restrict__ b_qkv,
        float* __restrict__ kv_ws,      // [BJ][H][16][16]
        float* __restrict__ ksum_ws) {  // [BJ][128]
    const int bj = blockIdx.y;
    const int b  = bj / J_;
    const int j  = bj % J_;
    const int c  = threadIdx.x;          // 0..255

    // Stage this thread's weight row (k: rows 128..255, v: rows 256..383)
    float wreg[d_];
    {
        const float* wr = w_qkv + (size_t)(d_ + c) * d_;
        #pragma unroll
        for (int k = 0; k < d_; ++k) wreg[k] = wr[k];
    }
    const float bq = b_qkv[d_ + c];

    __shared__ float sk[d_];   // k_m for current t
    __shared__ float sv[d_];   // v for current t

    // kv accumulation role: thread c -> head h = c>>5, i = (c&31)>>1, j0 = (c&1)*8
    const int h  = c >> 5;
    const int ii = (c & 31) >> 1;
    const int j0 = (c & 1) * 8;
    float acc_kv[8];
    #pragma unroll
    for (int q = 0; q < 8; ++q) acc_kv[q] = 0.f;
    float acc_ks = 0.f;

    const int t0 = blockIdx.x * (T_ / 8);
    for (int tt = 0; tt < T_ / 8; ++tt) {
        const int t = t0 + tt;
        const float* xrow = x + ((size_t)(b * T_ + t) * J_ + j) * D_ + 1;
        float acc = bq;
        #pragma unroll
        for (int k = 0; k < d_; ++k) acc = fmaf(xrow[k], wreg[k], acc);

        if (c < d_) {
            const float km = phi_f(acc);
            sk[c] = km;
            acc_ks += km;
        } else {
            sv[c - d_] = acc;
        }
        __syncthreads();

        const float kmv = sk[h * DH + ii];
        const float* vv = &sv[h * DH + j0];
        #pragma unroll
        for (int q = 0; q < 8; ++q) acc_kv[q] = fmaf(kmv, vv[q], acc_kv[q]);
        __syncthreads();
    }

    float* kvp = kv_ws + (((size_t)bj * H_ + h) * DH + ii) * DH + j0;
    #pragma unroll
    for (int q = 0; q < 8; ++q) atomicAdd(&kvp[q], acc_kv[q]);
    if (c < d_) atomicAdd(&ksum_ws[(size_t)bj * d_ + c], acc_ks);
}

// --------------------------------------------------------------------------
// Kernel 2: for each (bj, t-chunk): recompute q_m on the fly, then
// denom = q_m . ksum (per head, clipped), agg = (q_m @ kv) / denom,
// y = agg @ w_out^T + b_out, y_time = sqrt(1 + ||y||^2), write [y_time, y].
// Threads 0..127 own w_qkv rows 0..127 (q); threads 128..255 own w_out rows.
// --------------------------------------------------------------------------
__global__ __launch_bounds__(256) void k2_out(
        const float* __restrict__ x,
        const float* __restrict__ w_qkv,
        const float* __restrict__ b_qkv,
        const float* __restrict__ w_out,
        const float* __restrict__ b_out,
        const float* __restrict__ kv_ws,
        const float* __restrict__ ksum_ws,
        float* __restrict__ out) {
    const int bj = blockIdx.y;
    const int b  = bj / J_;
    const int j  = bj % J_;
    const int c  = threadIdx.x;
    const int cc = c & 127;
    const bool is_q = (c < d_);

    float wreg[d_];
    {
        const float* wr = is_q ? (w_qkv + (size_t)cc * d_)
                               : (w_out + (size_t)cc * d_);
        #pragma unroll
        for (int k = 0; k < d_; ++k) wreg[k] = wr[k];
    }
    const float bias = is_q ? b_qkv[cc] : b_out[cc];

    __shared__ float kv_s[H_ * DH * DH];   // 8 KB
    __shared__ float ks_s[d_];
    __shared__ float qm_s[d_];
    __shared__ float den_s[H_];
    __shared__ float ag_s[d_];
    __shared__ float y_s[d_];
    __shared__ float y2_s[d_];
    __shared__ float yt_s;

    for (int i = c; i < H_ * DH * DH; i += 256)
        kv_s[i] = kv_ws[(size_t)bj * (H_ * DH * DH) + i];
    if (c < d_) ks_s[c] = ksum_ws[(size_t)bj * d_ + c];
    __syncthreads();

    const int t0 = blockIdx.x * (T_ / 8);
    for (int tt = 0; tt < T_ / 8; ++tt) {
        const int t = t0 + tt;
        const size_t rowoff = ((size_t)(b * T_ + t) * J_ + j) * D_;
        const float* xrow = x + rowoff + 1;

        if (is_q) {
            float acc = bias;
            #pragma unroll
            for (int k = 0; k < d_; ++k) acc = fmaf(xrow[k], wreg[k], acc);
            qm_s[cc] = phi_f(acc);
        }
        __syncthreads();

        if (c < H_) {  // per-head denominator
            float s = 0.f;
            #pragma unroll
            for (int i = 0; i < DH; ++i) s += qm_s[c * DH + i] * ks_s[c * DH + i];
            den_s[c] = fmaxf(s, EPS_);
        }
        __syncthreads();

        if (!is_q) {   // agg column cc = h*16 + e
            const int hh = cc >> 4, e = cc & 15;
            float s = 0.f;
            #pragma unroll
            for (int i = 0; i < DH; ++i)
                s = fmaf(qm_s[hh * DH + i], kv_s[(hh * DH + i) * DH + e], s);
            ag_s[cc] = s / den_s[hh];
        }
        __syncthreads();

        if (!is_q) {   // out projection column cc
            float acc = bias;
            #pragma unroll
            for (int k = 0; k < d_; ++k) acc = fmaf(ag_s[k], wreg[k], acc);
            y_s[cc] = acc;
            y2_s[cc] = acc * acc;
        }
        __syncthreads();

        if (c < 64) {  // reduce ||y||^2 in wave 0
            float s = y2_s[c] + y2_s[c + 64];
            #pragma unroll
            for (int off = 32; off > 0; off >>= 1) s += __shfl_down(s, off, 64);
            if (c == 0) yt_s = sqrtf(1.f + s);
        }
        __syncthreads();

        float* orow = out + rowoff;
        if (c == 0) orow[0] = yt_s;
        if (c < d_) orow[1 + c] = y_s[c];
        __syncthreads();
    }
}

extern "C" void kernel_launch(void* const* d_in, const int* in_sizes, int n_in,
                              void* d_out, int out_size, void* d_ws, size_t ws_size,
                              hipStream_t stream) {
    const float* x      = (const float*)d_in[0];
    const float* w_qkv  = (const float*)d_in[1];
    const float* b_qkv  = (const float*)d_in[2];
    const float* w_out  = (const float*)d_in[3];
    const float* b_out  = (const float*)d_in[4];
    float* out = (float*)d_out;

    float* kv_ws   = (float*)d_ws;                              // BJ*H*16*16
    float* ksum_ws = kv_ws + (size_t)BJ_ * H_ * DH * DH;        // BJ*128
    const size_t zero_bytes =
        ((size_t)BJ_ * H_ * DH * DH + (size_t)BJ_ * d_) * sizeof(float);
    hipMemsetAsync(d_ws, 0, zero_bytes, stream);

    dim3 blk(256);
    dim3 grd(8, BJ_);
    hipLaunchKernelGGL(k1_kv, grd, blk, 0, stream, x, w_qkv, b_qkv, kv_ws, ksum_ws);
    hipLaunchKernelGGL(k2_out, grd, blk, 0, stream, x, w_qkv, b_qkv, w_out, b_out,
                       kv_ws, ksum_ws, out);
}

// Round 2
// 396.561 us; speedup vs baseline: 8.1076x; 8.1076x over previous
//
#include <hip/hip_runtime.h>
#include <math.h>

#define B_   8
#define T_   2048
#define J_   17
#define D_   129
#define d_   128
#define H_   8
#define BJ_  (B_ * J_)      // 136
#define EPS_ 1e-6f
#define CH   8              // t-chunks per bj
#define RPB  (T_ / CH)      // 256 rows per block
#define NIT  (RPB / 64)     // 4 tile iterations of 64 rows

typedef short bf8 __attribute__((ext_vector_type(8)));   // 8 bf16 in 4 VGPRs
typedef float fx4 __attribute__((ext_vector_type(4)));

__device__ __forceinline__ float phi_f(float x) {
    return x > 0.f ? x + 1.f : __expf(x);
}
__device__ __forceinline__ short f2b(float f) {            // fp32->bf16 RNE
    union { float f; unsigned u; } c; c.f = f;
    unsigned u = c.u + 0x7fffu + ((c.u >> 16) & 1u);
    return (short)(u >> 16);
}
__device__ __forceinline__ float b2f(short s) {
    union { float f; unsigned u; } c;
    c.u = ((unsigned)(unsigned short)s) << 16;
    return c.f;
}

// ============================================================================
// Pass A: k/v GEMM (cols 128..383 of qkv) + kv[h] += k_m^T v + ksum, per bj.
// Grid (CH, BJ), block 256 (4 waves). Wave w computes output cols 64w..64w+63.
// ============================================================================
__global__ __launch_bounds__(256, 2) void pass_kv(
        const float* __restrict__ x, const float* __restrict__ wqkv,
        const float* __restrict__ bqkv,
        float* __restrict__ kvw,       // [BJ][H][16(j=v-feat)][16(i=k-feat)]
        float* __restrict__ ksw) {     // [BJ][128]
    const int bj = blockIdx.y, b = bj / J_, j = bj % J_;
    const int t0 = blockIdx.x * RPB;
    const int tid = threadIdx.x, wave = tid >> 6, lane = tid & 63;
    const int quad = lane >> 4, l16 = lane & 15;

    __shared__ short sx[64 * 136];     // x tile, bf16, row-major, pad 8
    __shared__ short kT[128 * 72];     // k_m^T : [feat][t_local], pad 8
    __shared__ short vT[128 * 72];     // v^T

    // Register-resident B fragments: B[k][n] = W[n][k], n = 128 + 64w+16nt+l16
    bf8 wf[4][4];
    float bias[4];
    #pragma unroll
    for (int nt = 0; nt < 4; ++nt) {
        const int n = d_ + wave * 64 + nt * 16 + l16;
        bias[nt] = bqkv[n];
        #pragma unroll
        for (int ks = 0; ks < 4; ++ks) {
            const float* p = wqkv + (size_t)n * d_ + ks * 32 + quad * 8;
            bf8 t;
            #pragma unroll
            for (int q2 = 0; q2 < 8; ++q2) t[q2] = f2b(p[q2]);
            wf[nt][ks] = t;
        }
    }

    fx4 kva[2];
    kva[0] = (fx4){0.f, 0.f, 0.f, 0.f};
    kva[1] = (fx4){0.f, 0.f, 0.f, 0.f};
    float ksp[4] = {0.f, 0.f, 0.f, 0.f};

    for (int it = 0; it < NIT; ++it) {
        __syncthreads();
        {   // stage x tile -> bf16 LDS
            const int tb = t0 + it * 64;
            #pragma unroll
            for (int i = 0; i < 16; ++i) {
                const int F = tid + 256 * i, row = F >> 6, c2 = F & 63;
                const float* xr = x + ((size_t)((b * T_ + tb + row) * J_ + j)) * D_ + 1 + 2 * c2;
                *reinterpret_cast<unsigned*>(&sx[row * 136 + 2 * c2]) =
                    (unsigned)(unsigned short)f2b(xr[0]) |
                    ((unsigned)(unsigned short)f2b(xr[1]) << 16);
            }
        }
        __syncthreads();

        fx4 acc[4][4];
        #pragma unroll
        for (int nt = 0; nt < 4; ++nt)
            #pragma unroll
            for (int mt = 0; mt < 4; ++mt) acc[nt][mt] = (fx4){0.f, 0.f, 0.f, 0.f};

        #pragma unroll
        for (int ks = 0; ks < 4; ++ks) {
            bf8 af[4];
            #pragma unroll
            for (int mt = 0; mt < 4; ++mt)
                af[mt] = *reinterpret_cast<const bf8*>(
                    &sx[(mt * 16 + l16) * 136 + ks * 32 + quad * 8]);
            #pragma unroll
            for (int nt = 0; nt < 4; ++nt)
                #pragma unroll
                for (int mt = 0; mt < 4; ++mt)
                    acc[nt][mt] = __builtin_amdgcn_mfma_f32_16x16x32_bf16(
                        af[mt], wf[nt][ks], acc[nt][mt], 0, 0, 0);
        }

        // epilogue: bias (+phi for k), transpose-write to kT / vT
        {
            short* dst = (wave < 2) ? kT : vT;
            const int fbase = (wave & 1) * 64;
            const bool isk = (wave < 2);
            #pragma unroll
            for (int nt = 0; nt < 4; ++nt)
                #pragma unroll
                for (int mt = 0; mt < 4; ++mt) {
                    unsigned long long pk = 0ull;
                    #pragma unroll
                    for (int r = 0; r < 4; ++r) {
                        float v = acc[nt][mt][r] + bias[nt];
                        if (isk) { v = phi_f(v); ksp[nt] += v; }
                        pk |= ((unsigned long long)(unsigned short)f2b(v)) << (16 * r);
                    }
                    *reinterpret_cast<unsigned long long*>(
                        &dst[(fbase + nt * 16 + l16) * 72 + mt * 16 + quad * 4]) = pk;
                }
        }
        __syncthreads();

        // kv[h] += k_m^T(16 x 64t) * v(64t x 16): K = t, two 32-steps
        #pragma unroll
        for (int hh = 0; hh < 2; ++hh) {
            const int h = wave * 2 + hh;
            #pragma unroll
            for (int ks2 = 0; ks2 < 2; ++ks2) {
                bf8 ak = *reinterpret_cast<const bf8*>(
                    &kT[(h * 16 + l16) * 72 + ks2 * 32 + quad * 8]);
                bf8 bv = *reinterpret_cast<const bf8*>(
                    &vT[(h * 16 + l16) * 72 + ks2 * 32 + quad * 8]);
                kva[hh] = __builtin_amdgcn_mfma_f32_16x16x32_bf16(ak, bv, kva[hh], 0, 0, 0);
            }
        }
    }

    // commit: kv C layout col=l16=j(v-feat), row=quad*4+r=i(k-feat)
    #pragma unroll
    for (int hh = 0; hh < 2; ++hh) {
        const int h = wave * 2 + hh;
        float* p = kvw + (((size_t)bj * H_ + h) * 16 + l16) * 16 + quad * 4;
        #pragma unroll
        for (int r = 0; r < 4; ++r) atomicAdd(p + r, kva[hh][r]);
    }
    if (wave < 2) {
        #pragma unroll
        for (int nt = 0; nt < 4; ++nt) {
            float s = ksp[nt];
            s += __shfl_xor(s, 16);
            s += __shfl_xor(s, 32);
            if (lane < 16)
                atomicAdd(ksw + (size_t)bj * d_ + wave * 64 + nt * 16 + l16, s);
        }
    }
}

// ============================================================================
// Pass B: q GEMM -> phi -> denom -> agg (MFMA, K padded 16->32) -> out GEMM
// -> y_time + store. Grid (CH, BJ), block 256. Wave w owns cols 32w..32w+31.
// ============================================================================
__global__ __launch_bounds__(256, 2) void pass_out(
        const float* __restrict__ x, const float* __restrict__ wqkv,
        const float* __restrict__ bqkv, const float* __restrict__ wout,
        const float* __restrict__ bout,
        const float* __restrict__ kvw, const float* __restrict__ ksw,
        float* __restrict__ out) {
    const int bj = blockIdx.y, b = bj / J_, j = bj % J_;
    const int t0 = blockIdx.x * RPB;
    const int tid = threadIdx.x, wave = tid >> 6, lane = tid & 63;
    const int quad = lane >> 4, l16 = lane & 15;

    __shared__ short sx[64 * 136];
    __shared__ short qm[64 * 136];     // q_m bf16, row-major
    __shared__ short sag[64 * 136];    // agg bf16, row-major
    __shared__ short kvT[H_ * 16 * 24]; // [h][e(v-feat)][i(k-feat)] pad->24
    __shared__ float kss[d_];
    __shared__ float dens[64 * H_];
    __shared__ float rnorm[64];

    bf8 wqf[2][4], wof[2][4];
    float bq2[2], bo2[2];
    #pragma unroll
    for (int nt = 0; nt < 2; ++nt) {
        const int n = wave * 32 + nt * 16 + l16;
        bq2[nt] = bqkv[n];
        bo2[nt] = bout[n];
        #pragma unroll
        for (int ks = 0; ks < 4; ++ks) {
            const float* p = wqkv + (size_t)n * d_ + ks * 32 + quad * 8;
            const float* p2 = wout + (size_t)n * d_ + ks * 32 + quad * 8;
            bf8 t, t2;
            #pragma unroll
            for (int q2 = 0; q2 < 8; ++q2) { t[q2] = f2b(p[q2]); t2[q2] = f2b(p2[q2]); }
            wqf[nt][ks] = t;
            wof[nt][ks] = t2;
        }
    }
    // stage kv (transposed layout already in ws) and ksum
    #pragma unroll
    for (int i = 0; i < 8; ++i) {
        const int idx = tid + 256 * i;
        const int h = idx >> 8, jj = (idx >> 4) & 15, ii = idx & 15;
        kvT[(h * 16 + jj) * 24 + ii] =
            f2b(kvw[(((size_t)bj * H_ + h) * 16 + jj) * 16 + ii]);
    }
    if (tid < d_) kss[tid] = ksw[(size_t)bj * d_ + tid];

    for (int it = 0; it < NIT; ++it) {
        __syncthreads();
        {   // stage x tile
            const int tb = t0 + it * 64;
            #pragma unroll
            for (int i = 0; i < 16; ++i) {
                const int F = tid + 256 * i, row = F >> 6, c2 = F & 63;
                const float* xr = x + ((size_t)((b * T_ + tb + row) * J_ + j)) * D_ + 1 + 2 * c2;
                *reinterpret_cast<unsigned*>(&sx[row * 136 + 2 * c2]) =
                    (unsigned)(unsigned short)f2b(xr[0]) |
                    ((unsigned)(unsigned short)f2b(xr[1]) << 16);
            }
            if (tid < 64) rnorm[tid] = 0.f;
        }
        __syncthreads();

        // q GEMM
        fx4 acc[2][4];
        #pragma unroll
        for (int nt = 0; nt < 2; ++nt)
            #pragma unroll
            for (int mt = 0; mt < 4; ++mt) acc[nt][mt] = (fx4){0.f, 0.f, 0.f, 0.f};
        #pragma unroll
        for (int ks = 0; ks < 4; ++ks) {
            bf8 af[4];
            #pragma unroll
            for (int mt = 0; mt < 4; ++mt)
                af[mt] = *reinterpret_cast<const bf8*>(
                    &sx[(mt * 16 + l16) * 136 + ks * 32 + quad * 8]);
            #pragma unroll
            for (int nt = 0; nt < 2; ++nt)
                #pragma unroll
                for (int mt = 0; mt < 4; ++mt)
                    acc[nt][mt] = __builtin_amdgcn_mfma_f32_16x16x32_bf16(
                        af[mt], wqf[nt][ks], acc[nt][mt], 0, 0, 0);
        }
        #pragma unroll
        for (int nt = 0; nt < 2; ++nt) {
            const int col = wave * 32 + nt * 16 + l16;
            #pragma unroll
            for (int mt = 0; mt < 4; ++mt)
                #pragma unroll
                for (int r = 0; r < 4; ++r)
                    qm[(mt * 16 + quad * 4 + r) * 136 + col] =
                        f2b(phi_f(acc[nt][mt][r] + bq2[nt]));
        }
        __syncthreads();

        // denominators: 512 (row, h) tasks, 2 per thread
        #pragma unroll
        for (int u = 0; u < 2; ++u) {
            const int s2 = tid * 2 + u, row = s2 >> 3, h = s2 & 7;
            const short* qp = &qm[row * 136 + h * 16];
            float s = 0.f;
            #pragma unroll
            for (int i = 0; i < 16; ++i) s += b2f(qp[i]) * kss[h * 16 + i];
            dens[row * 8 + h] = fmaxf(s, EPS_);
        }
        __syncthreads();

        // agg = (q_m @ kv[h]) / denom, per head; K=16 padded to 32 with zeros
        #pragma unroll
        for (int hh = 0; hh < 2; ++hh) {
            const int h = wave * 2 + hh;
            bf8 bk = (bf8){0, 0, 0, 0, 0, 0, 0, 0};
            if (quad < 2)
                bk = *reinterpret_cast<const bf8*>(&kvT[(h * 16 + l16) * 24 + quad * 8]);
            #pragma unroll
            for (int mt = 0; mt < 4; ++mt) {
                bf8 aq = (bf8){0, 0, 0, 0, 0, 0, 0, 0};
                if (quad < 2)
                    aq = *reinterpret_cast<const bf8*>(
                        &qm[(mt * 16 + l16) * 136 + h * 16 + quad * 8]);
                fx4 ag = __builtin_amdgcn_mfma_f32_16x16x32_bf16(
                    aq, bk, (fx4){0.f, 0.f, 0.f, 0.f}, 0, 0, 0);
                #pragma unroll
                for (int r = 0; r < 4; ++r) {
                    const int row = mt * 16 + quad * 4 + r;
                    sag[row * 136 + h * 16 + l16] = f2b(ag[r] / dens[row * 8 + h]);
                }
            }
        }
        __syncthreads();

        // out GEMM + bias
        fx4 ya[2][4];
        #pragma unroll
        for (int nt = 0; nt < 2; ++nt)
            #pragma unroll
            for (int mt = 0; mt < 4; ++mt) ya[nt][mt] = (fx4){0.f, 0.f, 0.f, 0.f};
        #pragma unroll
        for (int ks = 0; ks < 4; ++ks) {
            bf8 af[4];
            #pragma unroll
            for (int mt = 0; mt < 4; ++mt)
                af[mt] = *reinterpret_cast<const bf8*>(
                    &sag[(mt * 16 + l16) * 136 + ks * 32 + quad * 8]);
            #pragma unroll
            for (int nt = 0; nt < 2; ++nt)
                #pragma unroll
                for (int mt = 0; mt < 4; ++mt)
                    ya[nt][mt] = __builtin_amdgcn_mfma_f32_16x16x32_bf16(
                        af[mt], wof[nt][ks], ya[nt][mt], 0, 0, 0);
        }

        // stores + row-norm
        const int tb = t0 + it * 64;
        #pragma unroll
        for (int mt = 0; mt < 4; ++mt) {
            float sq[4] = {0.f, 0.f, 0.f, 0.f};
            #pragma unroll
            for (int nt = 0; nt < 2; ++nt) {
                const int col = wave * 32 + nt * 16 + l16;
                #pragma unroll
                for (int r = 0; r < 4; ++r) {
                    const float y = ya[nt][mt][r] + bo2[nt];
                    const int t = tb + mt * 16 + quad * 4 + r;
                    out[((size_t)(b * T_ + t) * J_ + j) * D_ + 1 + col] = y;
                    sq[r] += y * y;
                }
            }
            #pragma unroll
            for (int r = 0; r < 4; ++r) {
                float s = sq[r];
                s += __shfl_xor(s, 1);
                s += __shfl_xor(s, 2);
                s += __shfl_xor(s, 4);
                s += __shfl_xor(s, 8);
                if (l16 == 0) atomicAdd(&rnorm[mt * 16 + quad * 4 + r], s);
            }
        }
        __syncthreads();
        if (tid < 64) {
            const int t = tb + tid;
            out[((size_t)(b * T_ + t) * J_ + j) * D_] = sqrtf(1.f + rnorm[tid]);
        }
    }
}

extern "C" void kernel_launch(void* const* d_in, const int* in_sizes, int n_in,
                              void* d_out, int out_size, void* d_ws, size_t ws_size,
                              hipStream_t stream) {
    const float* x     = (const float*)d_in[0];
    const float* wqkv  = (const float*)d_in[1];
    const float* bqkv  = (const float*)d_in[2];
    const float* wout  = (const float*)d_in[3];
    const float* bout  = (const float*)d_in[4];
    float* out = (float*)d_out;

    float* kvw = (float*)d_ws;                          // BJ*H*16*16 fp32
    float* ksw = kvw + (size_t)BJ_ * H_ * 16 * 16;      // BJ*128 fp32
    const size_t zero_bytes =
        ((size_t)BJ_ * H_ * 16 * 16 + (size_t)BJ_ * d_) * sizeof(float);
    hipMemsetAsync(d_ws, 0, zero_bytes, stream);

    dim3 blk(256);
    dim3 grd(CH, BJ_);
    hipLaunchKernelGGL(pass_kv, grd, blk, 0, stream, x, wqkv, bqkv, kvw, ksw);
    hipLaunchKernelGGL(pass_out, grd, blk, 0, stream, x, wqkv, bqkv, wout, bout,
                       kvw, ksw, out);
}